// Round 2
// baseline (1330.779 us; speedup 1.0000x reference)
//
#include <hip/hip_runtime.h>
#include <hip/hip_bf16.h>
#include <stdint.h>

// SparseMOE on MI355X (gfx950). Inputs/outputs are FLOAT32 (per reference dtypes);
// GEMM compute uses bf16 MFMA with on-the-fly f32->bf16 conversion in LDS staging.
// Pipeline: router -> scan -> fill -> GEMM1 (x@w1, x@w2, fused SiLU) -> GEMM2 (h@wo, weighted) -> combine.

#define T_TOKENS 4096
#define DM 1024
#define DH 4096
#define N_EXP 8
#define N_PAIRS (T_TOKENS * 2)   // 8192 token-expert pairs (top-2, distinct experts)
#define MAX_TILES 96             // worst-case sum ceil(N_e/128) = 71

typedef __hip_bfloat16 bf16_t;
typedef __bf16 bf16x8 __attribute__((ext_vector_type(8)));   // MFMA A/B frag (4 VGPRs)
typedef float  f32x4  __attribute__((ext_vector_type(4)));   // MFMA C/D frag
typedef unsigned short ushort4v __attribute__((ext_vector_type(4)));

// ---- workspace layout (byte offsets); total ~85 MB (confirmed available in R1) ----
#define WS_COUNTS   0        // int[8]   tokens per expert (atomic)
#define WS_OFFSETS  32       // int[8]   exclusive scan
#define WS_PSUM     96       // float[8] sum of probs per expert (atomic)
#define WS_NTILES   128      // int
#define WS_TILE_E   256      // int[128] tile -> expert
#define WS_TILE_M0  768      // int[128] tile -> first slot
#define WS_E_OF     4096     // int[8192]   (t,k) -> expert
#define WS_POS_OF   36864    // int[8192]   (t,k) -> pos within expert
#define WS_W_OF     69632    // float[8192] (t,k) -> gate weight
#define WS_TOK_OF   102400   // int[8192]   slot -> token
#define WS_WT_OF    135168   // float[8192] slot -> gate weight
#define WS_SLOT_OF  167936   // int[8192]   (t,k) -> slot
#define WS_HBUF     (1u<<20)                              // bf16[8192][4096] = 64 MB
#define WS_YPAIR    (WS_HBUF + (size_t)N_PAIRS*DH*2)      // bf16[8192][1024] = 16 MB
#define WS_NEEDED   (WS_YPAIR + (size_t)N_PAIRS*DM*2)     // ~81 MB

#define PITCH 40   // LDS row pitch (elems): 80 B rows keep ds_read_b128 16B-aligned.
                   // B-transpose b32 writes are 4-way bank-conflicted (known, fix later).

__device__ __forceinline__ unsigned short f2bf(float f) {
  bf16_t h = __float2bfloat16(f);   // RNE
  return *(unsigned short*)&h;
}

// ---------------- router: 1 wave per token ----------------
__global__ __launch_bounds__(64) void k_router(const float* __restrict__ x,
                                               const float* __restrict__ rw,
                                               const float* __restrict__ rb,
                                               char* __restrict__ ws) {
  int t = blockIdx.x, lane = threadIdx.x;
  float acc[8];
#pragma unroll
  for (int e = 0; e < 8; ++e) acc[e] = 0.f;
  const float* xr = x + (size_t)t * DM;
  for (int j = lane; j < DM; j += 64) {
    float xv = xr[j];
    const float* r = rw + j * 8;   // router_w is [DM][8]
#pragma unroll
    for (int e = 0; e < 8; ++e) acc[e] += xv * r[e];
  }
#pragma unroll
  for (int off = 32; off >= 1; off >>= 1) {
#pragma unroll
    for (int e = 0; e < 8; ++e) acc[e] += __shfl_down(acc[e], off);
  }
  if (lane == 0) {
    float mx = -1e30f;
#pragma unroll
    for (int e = 0; e < 8; ++e) { acc[e] += rb[e]; mx = fmaxf(mx, acc[e]); }
    float s = 0.f;
#pragma unroll
    for (int e = 0; e < 8; ++e) { acc[e] = __expf(acc[e] - mx); s += acc[e]; }
    float inv = 1.f / s;
#pragma unroll
    for (int e = 0; e < 8; ++e) acc[e] *= inv;
    float* psum = (float*)(ws + WS_PSUM);
#pragma unroll
    for (int e = 0; e < 8; ++e) atomicAdd(&psum[e], acc[e]);
    // top-2, earliest index on ties (matches jax.lax.top_k)
    int i1 = 0;
#pragma unroll
    for (int e = 1; e < 8; ++e) if (acc[e] > acc[i1]) i1 = e;
    int i2 = -1;
#pragma unroll
    for (int e = 0; e < 8; ++e) if (e != i1 && (i2 < 0 || acc[e] > acc[i2])) i2 = e;
    int* counts = (int*)(ws + WS_COUNTS);
    int* e_of = (int*)(ws + WS_E_OF);
    int* pos_of = (int*)(ws + WS_POS_OF);
    float* w_of = (float*)(ws + WS_W_OF);
    int sel[2] = {i1, i2};
#pragma unroll
    for (int k = 0; k < 2; ++k) {
      int e = sel[k];
      int pos = atomicAdd(&counts[e], 1);
      e_of[2 * t + k] = e; pos_of[2 * t + k] = pos; w_of[2 * t + k] = acc[e];
    }
  }
}

// ---------------- scan: offsets, tile table, lb_loss ----------------
__global__ void k_scan(char* __restrict__ ws, float* __restrict__ out) {
  if (threadIdx.x == 0 && blockIdx.x == 0) {
    int* counts = (int*)(ws + WS_COUNTS);
    int* offs = (int*)(ws + WS_OFFSETS);
    int* te = (int*)(ws + WS_TILE_E);
    int* tm = (int*)(ws + WS_TILE_M0);
    int off = 0, nt = 0;
    for (int e = 0; e < 8; ++e) {
      offs[e] = off;
      for (int m0 = 0; m0 < counts[e]; m0 += 128) { te[nt] = e; tm[nt] = off + m0; ++nt; }
      off += counts[e];
    }
    *(int*)(ws + WS_NTILES) = nt;
    float* psum = (float*)(ws + WS_PSUM);
    float lb = 0.f;
    for (int e = 0; e < 8; ++e)
      lb += ((float)counts[e] / (float)T_TOKENS) * (psum[e] / (float)T_TOKENS);
    lb *= 0.01f * 8.f;
    out[(size_t)T_TOKENS * DM] = lb;
  }
}

// ---------------- fill: (t,k) -> slot tables ----------------
__global__ __launch_bounds__(256) void k_fill(char* __restrict__ ws) {
  int i = blockIdx.x * 256 + threadIdx.x;
  if (i < N_PAIRS) {
    const int* offs = (const int*)(ws + WS_OFFSETS);
    int e = ((const int*)(ws + WS_E_OF))[i];
    int slot = offs[e] + ((const int*)(ws + WS_POS_OF))[i];
    ((int*)(ws + WS_TOK_OF))[slot] = i >> 1;
    ((float*)(ws + WS_WT_OF))[slot] = ((const float*)(ws + WS_W_OF))[i];
    ((int*)(ws + WS_SLOT_OF))[i] = slot;
  }
}

// ---------------- GEMM1: H = (X@W1+b1) * silu(X@W2+b2), gathered rows ----------------
// block: 256 thr = 4 waves (2x2), BM=128 tokens, BN=64 hidden cols, BK=32, dual acc (w1,w2)
__global__ __launch_bounds__(256, 2) void k_gemm1(const float* __restrict__ x,
                                                  const float* __restrict__ w1,
                                                  const float* __restrict__ b1,
                                                  const float* __restrict__ w2,
                                                  const float* __restrict__ b2,
                                                  char* __restrict__ ws) {
  __shared__ __align__(16) unsigned short As[128 * PITCH];
  __shared__ __align__(16) unsigned short Bs1[64 * PITCH];
  __shared__ __align__(16) unsigned short Bs2[64 * PITCH];
  __shared__ int tokLds[128];
  int tid = threadIdx.x;
  int tileIdx = blockIdx.y;
  if (tileIdx >= *(const int*)(ws + WS_NTILES)) return;
  int e = ((const int*)(ws + WS_TILE_E))[tileIdx];
  int m_start = ((const int*)(ws + WS_TILE_M0))[tileIdx];
  int m_end = ((const int*)(ws + WS_OFFSETS))[e] + ((const int*)(ws + WS_COUNTS))[e];
  int m_cnt = min(128, m_end - m_start);
  int n0 = blockIdx.x * 64;
  const int* tok_of = (const int*)(ws + WS_TOK_OF);
  if (tid < 128) tokLds[tid] = tok_of[m_start + min(tid, m_cnt - 1)];

  f32x4 acc1[4][2], acc2[4][2];
  f32x4 z = {0.f, 0.f, 0.f, 0.f};
#pragma unroll
  for (int i = 0; i < 4; ++i)
#pragma unroll
    for (int j = 0; j < 2; ++j) { acc1[i][j] = z; acc2[i][j] = z; }

  int lane = tid & 63, wave = tid >> 6;
  int wm = wave >> 1, wn = wave & 1;
  int lr = lane & 15, quad = lane >> 4;
  // B staging: 128 threads per matrix, each a 2k x 8n patch
  int q = tid & 127, mat = tid >> 7;
  int pk = (q & 15) * 2, pn = (q >> 4) * 8;
  const float* Wm = mat ? w2 : w1;
  unsigned short* BsM = mat ? Bs2 : Bs1;

  for (int kt = 0; kt < DM / 32; ++kt) {
    int k0 = kt * 32;
    __syncthreads();
    // stage A: 128 rows x 32 k (f32 gather -> bf16 LDS); 4x float4 per thread
#pragma unroll
    for (int h = 0; h < 4; ++h) {
      int c = tid + h * 256;
      int row = c >> 3, kc = (c & 7) * 4;
      const float* src = x + (size_t)tokLds[row] * DM + k0 + kc;
      float4 v = *(const float4*)src;
      ushort4v wv = { f2bf(v.x), f2bf(v.y), f2bf(v.z), f2bf(v.w) };
      *(ushort4v*)&As[row * PITCH + kc] = wv;
    }
    // stage B (transpose [k][n] -> LDS [n][k] bf16 k-pairs): 4x float4 loads, 8 b32 writes
    {
      const float* src = Wm + ((size_t)e * DM + k0 + pk) * DH + n0 + pn;
      float4 ra0 = *(const float4*)src;
      float4 ra1 = *(const float4*)(src + 4);
      float4 rb0 = *(const float4*)(src + DH);
      float4 rb1 = *(const float4*)(src + DH + 4);
      float av[8] = {ra0.x, ra0.y, ra0.z, ra0.w, ra1.x, ra1.y, ra1.z, ra1.w};
      float bv[8] = {rb0.x, rb0.y, rb0.z, rb0.w, rb1.x, rb1.y, rb1.z, rb1.w};
#pragma unroll
      for (int j = 0; j < 8; ++j) {
        unsigned int wv = (unsigned int)f2bf(av[j]) | ((unsigned int)f2bf(bv[j]) << 16);
        *(unsigned int*)&BsM[(pn + j) * PITCH + pk] = wv;
      }
    }
    __syncthreads();
    bf16x8 a[4], f1[2], f2v[2];
#pragma unroll
    for (int mt = 0; mt < 4; ++mt)
      a[mt] = *(const bf16x8*)&As[(wm * 64 + mt * 16 + lr) * PITCH + quad * 8];
#pragma unroll
    for (int nt = 0; nt < 2; ++nt) {
      f1[nt]  = *(const bf16x8*)&Bs1[(wn * 32 + nt * 16 + lr) * PITCH + quad * 8];
      f2v[nt] = *(const bf16x8*)&Bs2[(wn * 32 + nt * 16 + lr) * PITCH + quad * 8];
    }
#pragma unroll
    for (int mt = 0; mt < 4; ++mt)
#pragma unroll
      for (int nt = 0; nt < 2; ++nt) {
        acc1[mt][nt] = __builtin_amdgcn_mfma_f32_16x16x32_bf16(a[mt], f1[nt],  acc1[mt][nt], 0, 0, 0);
        acc2[mt][nt] = __builtin_amdgcn_mfma_f32_16x16x32_bf16(a[mt], f2v[nt], acc2[mt][nt], 0, 0, 0);
      }
  }
  // epilogue: h = (t1+b1) * silu(t2+b2)  -> Hbuf bf16
  bf16_t* Hbuf = (bf16_t*)(ws + WS_HBUF);
#pragma unroll
  for (int mt = 0; mt < 4; ++mt) {
    int growb = wm * 64 + mt * 16 + quad * 4;   // C/D: row=(lane>>4)*4+reg, col=lane&15
#pragma unroll
    for (int nt = 0; nt < 2; ++nt) {
      int col = n0 + wn * 32 + nt * 16 + lr;
      float b1v = b1[e * DH + col];
      float b2v = b2[e * DH + col];
#pragma unroll
      for (int r = 0; r < 4; ++r) {
        int grow = growb + r;
        if (grow < m_cnt) {
          float v1 = acc1[mt][nt][r] + b1v;
          float v2 = acc2[mt][nt][r] + b2v;
          float hh = v1 * (v2 / (1.f + __expf(-v2)));
          Hbuf[(size_t)(m_start + grow) * DH + col] = __float2bfloat16(hh);
        }
      }
    }
  }
}

// ---------------- GEMM2: Y = wt * (H@wo + bo) per pair ----------------
// block: 256 thr = 4 waves (2x2), BM=128 slots, BN=128 model cols, BK=32, K=4096
__global__ __launch_bounds__(256, 2) void k_gemm2(const float* __restrict__ wo,
                                                  const float* __restrict__ bo,
                                                  char* __restrict__ ws) {
  __shared__ __align__(16) unsigned short As[128 * PITCH];
  __shared__ __align__(16) unsigned short Bs[128 * PITCH];
  int tid = threadIdx.x;
  int tileIdx = blockIdx.y;
  if (tileIdx >= *(const int*)(ws + WS_NTILES)) return;
  int e = ((const int*)(ws + WS_TILE_E))[tileIdx];
  int m_start = ((const int*)(ws + WS_TILE_M0))[tileIdx];
  int m_end = ((const int*)(ws + WS_OFFSETS))[e] + ((const int*)(ws + WS_COUNTS))[e];
  int m_cnt = min(128, m_end - m_start);
  int n0 = blockIdx.x * 128;
  const bf16_t* Hbuf = (const bf16_t*)(ws + WS_HBUF);

  f32x4 acc[4][4];
  f32x4 z = {0.f, 0.f, 0.f, 0.f};
#pragma unroll
  for (int i = 0; i < 4; ++i)
#pragma unroll
    for (int j = 0; j < 4; ++j) acc[i][j] = z;

  int lane = tid & 63, wave = tid >> 6;
  int wm = wave >> 1, wn = wave & 1;
  int lr = lane & 15, quad = lane >> 4;
  int pk = (tid & 15) * 2, pn = (tid >> 4) * 8;   // 256 patches of 2k x 8n

  for (int kt = 0; kt < DH / 32; ++kt) {
    int k0 = kt * 32;
    __syncthreads();
    // stage A from Hbuf (bf16, already internal): 2x int4 per thread
#pragma unroll
    for (int h = 0; h < 2; ++h) {
      int c = tid + h * 256;
      int row = c >> 2, kc = (c & 3) * 8;
      int hrow = m_start + min(row, m_cnt - 1);   // clamp: stay in written Hbuf
      *(int4*)&As[row * PITCH + kc] = *(const int4*)(Hbuf + (size_t)hrow * DH + k0 + kc);
    }
    // stage B (wo f32 -> bf16, transpose): 4x float4 loads, 8 b32 writes
    {
      const float* src = wo + ((size_t)e * DH + k0 + pk) * DM + n0 + pn;
      float4 ra0 = *(const float4*)src;
      float4 ra1 = *(const float4*)(src + 4);
      float4 rb0 = *(const float4*)(src + DM);
      float4 rb1 = *(const float4*)(src + DM + 4);
      float av[8] = {ra0.x, ra0.y, ra0.z, ra0.w, ra1.x, ra1.y, ra1.z, ra1.w};
      float bv[8] = {rb0.x, rb0.y, rb0.z, rb0.w, rb1.x, rb1.y, rb1.z, rb1.w};
#pragma unroll
      for (int j = 0; j < 8; ++j) {
        unsigned int wv = (unsigned int)f2bf(av[j]) | ((unsigned int)f2bf(bv[j]) << 16);
        *(unsigned int*)&Bs[(pn + j) * PITCH + pk] = wv;
      }
    }
    __syncthreads();
    bf16x8 a[4], b[4];
#pragma unroll
    for (int mt = 0; mt < 4; ++mt)
      a[mt] = *(const bf16x8*)&As[(wm * 64 + mt * 16 + lr) * PITCH + quad * 8];
#pragma unroll
    for (int nt = 0; nt < 4; ++nt)
      b[nt] = *(const bf16x8*)&Bs[(wn * 64 + nt * 16 + lr) * PITCH + quad * 8];
#pragma unroll
    for (int mt = 0; mt < 4; ++mt)
#pragma unroll
      for (int nt = 0; nt < 4; ++nt)
        acc[mt][nt] = __builtin_amdgcn_mfma_f32_16x16x32_bf16(a[mt], b[nt], acc[mt][nt], 0, 0, 0);
  }
  bf16_t* Ypair = (bf16_t*)(ws + WS_YPAIR);
  const float* wts = (const float*)(ws + WS_WT_OF);
#pragma unroll
  for (int mt = 0; mt < 4; ++mt) {
    int growb = wm * 64 + mt * 16 + quad * 4;
#pragma unroll
    for (int nt = 0; nt < 4; ++nt) {
      int col = n0 + wn * 64 + nt * 16 + lr;
      float bov = bo[e * DM + col];
#pragma unroll
      for (int r = 0; r < 4; ++r) {
        int grow = growb + r;
        if (grow < m_cnt) {
          int slot = m_start + grow;
          Ypair[(size_t)slot * DM + col] = __float2bfloat16((acc[mt][nt][r] + bov) * wts[slot]);
        }
      }
    }
  }
}

// ---------------- combine: out[t] = Y[slot(t,0)] + Y[slot(t,1)]  (f32 out) ----------------
__global__ __launch_bounds__(256) void k_combine(const char* __restrict__ ws,
                                                 float* __restrict__ out) {
  int idx = blockIdx.x * 256 + threadIdx.x;          // 524288 threads, 8 cols each
  int t = idx >> 7, c = (idx & 127) * 8;
  const int* slot_of = (const int*)(ws + WS_SLOT_OF);
  int s0 = slot_of[2 * t], s1 = slot_of[2 * t + 1];
  const unsigned short* Y = (const unsigned short*)(ws + WS_YPAIR);
  int4 ya = *(const int4*)(Y + (size_t)s0 * DM + c);
  int4 yb = *(const int4*)(Y + (size_t)s1 * DM + c);
  const unsigned short* pa = (const unsigned short*)&ya;
  const unsigned short* pb = (const unsigned short*)&yb;
  float res[8];
#pragma unroll
  for (int j = 0; j < 8; ++j) {
    res[j] = __uint_as_float((unsigned int)pa[j] << 16) +
             __uint_as_float((unsigned int)pb[j] << 16);
  }
  float4 o0 = {res[0], res[1], res[2], res[3]};
  float4 o1 = {res[4], res[5], res[6], res[7]};
  *(float4*)(out + (size_t)t * DM + c) = o0;
  *(float4*)(out + (size_t)t * DM + c + 4) = o1;
}

extern "C" void kernel_launch(void* const* d_in, const int* in_sizes, int n_in,
                              void* d_out, int out_size, void* d_ws, size_t ws_size,
                              hipStream_t stream) {
  const float* x  = (const float*)d_in[0];
  const float* rw = (const float*)d_in[1];
  const float* rb = (const float*)d_in[2];
  const float* w1 = (const float*)d_in[3];
  const float* b1 = (const float*)d_in[4];
  const float* w2 = (const float*)d_in[5];
  const float* b2 = (const float*)d_in[6];
  const float* wo = (const float*)d_in[7];
  const float* bo = (const float*)d_in[8];
  float* out = (float*)d_out;
  char* ws = (char*)d_ws;
  if (ws_size < WS_NEEDED) return;  // diagnostic clean-fail if scratch too small

  hipMemsetAsync(d_ws, 0, 4096, stream);  // zero counts/psum/ntiles (ws is 0xAA-poisoned)
  k_router<<<T_TOKENS, 64, 0, stream>>>(x, rw, rb, ws);
  k_scan<<<1, 64, 0, stream>>>(ws, out);
  k_fill<<<N_PAIRS / 256, 256, 0, stream>>>(ws);
  k_gemm1<<<dim3(DH / 64, MAX_TILES), 256, 0, stream>>>(x, w1, b1, w2, b2, ws);
  k_gemm2<<<dim3(DM / 128, MAX_TILES), 256, 0, stream>>>(wo, bo, ws);
  k_combine<<<(T_TOKENS * DM / 8) / 256, 256, 0, stream>>>(ws, out);
}

// Round 3
// 1196.728 us; speedup vs baseline: 1.1120x; 1.1120x over previous
//
#include <hip/hip_runtime.h>
#include <hip/hip_bf16.h>
#include <stdint.h>

// SparseMOE on MI355X (gfx950). Inputs/outputs FLOAT32; GEMMs use bf16 MFMA with
// on-the-fly f32->bf16 conversion in LDS staging.
// R3: router atomics fixed (two-level reduction: 41k same-line atomics -> ~1.3k),
//     slot assignment via block-level LDS ranking in k_fill,
//     GEMMs get register-prefetch pipeline (global loads overlap MFMA).

#define T_TOKENS 4096
#define DM 1024
#define DH 4096
#define N_EXP 8
#define N_PAIRS (T_TOKENS * 2)
#define MAX_TILES 96             // worst-case sum ceil(N_e/128) = 71

typedef __hip_bfloat16 bf16_t;
typedef __bf16 bf16x8 __attribute__((ext_vector_type(8)));   // MFMA A/B frag (4 VGPRs)
typedef float  f32x4  __attribute__((ext_vector_type(4)));   // MFMA C/D frag
typedef unsigned short ushort4v __attribute__((ext_vector_type(4)));

// ---- workspace layout (byte offsets); ~81 MB (confirmed available) ----
#define WS_COUNTS   0        // int[8]   tokens per expert
#define WS_OFFSETS  32       // int[8]   exclusive scan
#define WS_PSUM     96       // float[8] sum of probs per expert
#define WS_NTILES   128      // int
#define WS_CURSOR   192      // int[8]   slot-assignment cursors (k_fill)
#define WS_TILE_E   256      // int[128] tile -> expert
#define WS_TILE_M0  768      // int[128] tile -> first slot
#define WS_E_OF     4096     // int[8192]   (t,k) -> expert
#define WS_W_OF     69632    // float[8192] (t,k) -> gate weight
#define WS_TOK_OF   102400   // int[8192]   slot -> token
#define WS_WT_OF    135168   // float[8192] slot -> gate weight
#define WS_SLOT_OF  167936   // int[8192]   (t,k) -> slot
#define WS_HBUF     (1u<<20)                              // bf16[8192][4096] = 64 MB
#define WS_YPAIR    (WS_HBUF + (size_t)N_PAIRS*DH*2)      // bf16[8192][1024] = 16 MB
#define WS_NEEDED   (WS_YPAIR + (size_t)N_PAIRS*DM*2)

#define PITCH 40   // LDS row pitch (elems): 80 B rows keep ds_read_b128 16B-aligned.

__device__ __forceinline__ unsigned short f2bf(float f) {
  bf16_t h = __float2bfloat16(f);   // RNE
  return *(unsigned short*)&h;
}

// ---------------- router: 64 blocks x 256 thr; wave handles 16 tokens ----------------
#define RT_BLOCKS 64
#define RT_TPB (T_TOKENS / RT_BLOCKS)   // 64 tokens per block
#define RT_TPW (RT_TPB / 4)             // 16 tokens per wave

__global__ __launch_bounds__(256) void k_router(const float* __restrict__ x,
                                                const float* __restrict__ rw,
                                                const float* __restrict__ rb,
                                                char* __restrict__ ws) {
  __shared__ float s_psum[4][8];
  __shared__ unsigned long long s_hist[4];
  int tid = threadIdx.x, lane = tid & 63, wave = tid >> 6;
  int t0 = blockIdx.x * RT_TPB + wave * RT_TPW;
  int* e_of = (int*)(ws + WS_E_OF);
  float* w_of = (float*)(ws + WS_W_OF);

  float lpsum[8];
#pragma unroll
  for (int e = 0; e < 8; ++e) lpsum[e] = 0.f;
  unsigned long long lhist = 0ull;

  for (int tt = 0; tt < RT_TPW; ++tt) {
    int t = t0 + tt;
    float acc[8];
#pragma unroll
    for (int e = 0; e < 8; ++e) acc[e] = 0.f;
    const float* xr = x + (size_t)t * DM;
    for (int j = lane; j < DM; j += 64) {
      float xv = xr[j];
      float4 r01 = *(const float4*)(rw + j * 8);
      float4 r23 = *(const float4*)(rw + j * 8 + 4);
      acc[0] += xv * r01.x; acc[1] += xv * r01.y;
      acc[2] += xv * r01.z; acc[3] += xv * r01.w;
      acc[4] += xv * r23.x; acc[5] += xv * r23.y;
      acc[6] += xv * r23.z; acc[7] += xv * r23.w;
    }
    // xor-butterfly: all lanes end with identical sums (fp add is commutative)
#pragma unroll
    for (int m = 1; m < 64; m <<= 1) {
#pragma unroll
      for (int e = 0; e < 8; ++e) acc[e] += __shfl_xor(acc[e], m);
    }
    float mx = -1e30f;
#pragma unroll
    for (int e = 0; e < 8; ++e) { acc[e] += rb[e]; mx = fmaxf(mx, acc[e]); }
    float s = 0.f;
#pragma unroll
    for (int e = 0; e < 8; ++e) { acc[e] = __expf(acc[e] - mx); s += acc[e]; }
    float inv = 1.f / s;
#pragma unroll
    for (int e = 0; e < 8; ++e) { acc[e] *= inv; lpsum[e] += acc[e]; }
    // top-2, earliest index on ties (matches jax.lax.top_k)
    int i1 = 0;
#pragma unroll
    for (int e = 1; e < 8; ++e) if (acc[e] > acc[i1]) i1 = e;
    int i2 = -1;
#pragma unroll
    for (int e = 0; e < 8; ++e) if (e != i1 && (i2 < 0 || acc[e] > acc[i2])) i2 = e;
    lhist += (1ull << (i1 * 8)) + (1ull << (i2 * 8));
    if (lane == 0) {
      e_of[2 * t] = i1; e_of[2 * t + 1] = i2;
      w_of[2 * t] = acc[i1]; w_of[2 * t + 1] = acc[i2];
    }
  }
  if (lane == 0) {
#pragma unroll
    for (int e = 0; e < 8; ++e) s_psum[wave][e] = lpsum[e];
    s_hist[wave] = lhist;
  }
  __syncthreads();
  if (tid < 8) {
    float p = s_psum[0][tid] + s_psum[1][tid] + s_psum[2][tid] + s_psum[3][tid];
    atomicAdd((float*)(ws + WS_PSUM) + tid, p);
    int c = 0;
#pragma unroll
    for (int w = 0; w < 4; ++w) c += (int)((s_hist[w] >> (tid * 8)) & 0xff);
    atomicAdd((int*)(ws + WS_COUNTS) + tid, c);
  }
}

// ---------------- scan: offsets, tile table, lb_loss ----------------
__global__ void k_scan(char* __restrict__ ws, float* __restrict__ out) {
  if (threadIdx.x == 0 && blockIdx.x == 0) {
    int* counts = (int*)(ws + WS_COUNTS);
    int* offs = (int*)(ws + WS_OFFSETS);
    int* te = (int*)(ws + WS_TILE_E);
    int* tm = (int*)(ws + WS_TILE_M0);
    int off = 0, nt = 0;
    for (int e = 0; e < 8; ++e) {
      offs[e] = off;
      for (int m0 = 0; m0 < counts[e]; m0 += 128) { te[nt] = e; tm[nt] = off + m0; ++nt; }
      off += counts[e];
    }
    *(int*)(ws + WS_NTILES) = nt;
    float* psum = (float*)(ws + WS_PSUM);
    float lb = 0.f;
    for (int e = 0; e < 8; ++e)
      lb += ((float)counts[e] / (float)T_TOKENS) * (psum[e] / (float)T_TOKENS);
    lb *= 0.01f * 8.f;
    out[(size_t)T_TOKENS * DM] = lb;
  }
}

// ---------------- fill: (t,k) -> slot via block-level ranking ----------------
__global__ __launch_bounds__(256) void k_fill(char* __restrict__ ws) {
  __shared__ int hist[8];
  __shared__ int base[8];
  int tid = threadIdx.x;
  int i = blockIdx.x * 256 + tid;     // N_PAIRS divisible by 256
  if (tid < 8) hist[tid] = 0;
  __syncthreads();
  int e = ((const int*)(ws + WS_E_OF))[i];
  int rank = atomicAdd(&hist[e], 1);  // LDS atomic: within-block rank
  __syncthreads();
  if (tid < 8) base[tid] = atomicAdd((int*)(ws + WS_CURSOR) + tid, hist[tid]);
  __syncthreads();
  int slot = ((const int*)(ws + WS_OFFSETS))[e] + base[e] + rank;
  ((int*)(ws + WS_TOK_OF))[slot] = i >> 1;
  ((float*)(ws + WS_WT_OF))[slot] = ((const float*)(ws + WS_W_OF))[i];
  ((int*)(ws + WS_SLOT_OF))[i] = slot;
}

// ---------------- GEMM1: H = (X@W1+b1) * silu(X@W2+b2), gathered rows ----------------
// 256 thr = 4 waves (2x2), BM=128 tokens, BN=64 hidden cols, BK=32, dual acc (w1,w2)
__global__ __launch_bounds__(256, 2) void k_gemm1(const float* __restrict__ x,
                                                  const float* __restrict__ w1,
                                                  const float* __restrict__ b1,
                                                  const float* __restrict__ w2,
                                                  const float* __restrict__ b2,
                                                  char* __restrict__ ws) {
  __shared__ __align__(16) unsigned short As[128 * PITCH];
  __shared__ __align__(16) unsigned short Bs1[64 * PITCH];
  __shared__ __align__(16) unsigned short Bs2[64 * PITCH];
  __shared__ int tokLds[128];
  int tid = threadIdx.x;
  int tileIdx = blockIdx.y;
  if (tileIdx >= *(const int*)(ws + WS_NTILES)) return;
  int e = ((const int*)(ws + WS_TILE_E))[tileIdx];
  int m_start = ((const int*)(ws + WS_TILE_M0))[tileIdx];
  int m_end = ((const int*)(ws + WS_OFFSETS))[e] + ((const int*)(ws + WS_COUNTS))[e];
  int m_cnt = min(128, m_end - m_start);
  int n0 = blockIdx.x * 64;
  if (tid < 128) tokLds[tid] = ((const int*)(ws + WS_TOK_OF))[m_start + min(tid, m_cnt - 1)];
  __syncthreads();

  f32x4 acc1[4][2], acc2[4][2];
  f32x4 z = {0.f, 0.f, 0.f, 0.f};
#pragma unroll
  for (int i = 0; i < 4; ++i)
#pragma unroll
    for (int j = 0; j < 2; ++j) { acc1[i][j] = z; acc2[i][j] = z; }

  int lane = tid & 63, wave = tid >> 6;
  int wm = wave >> 1, wn = wave & 1;
  int lr = lane & 15, quad = lane >> 4;
  // B staging: 128 threads per matrix, each a 2k x 8n patch
  int q = tid & 127, mat = tid >> 7;
  int pk = (q & 15) * 2, pn = (q >> 4) * 8;
  const float* Wm = mat ? w2 : w1;
  unsigned short* BsM = mat ? Bs2 : Bs1;
  const float* bBase = Wm + ((size_t)e * DM + pk) * DH + n0 + pn;

  // A staging geometry (fixed per thread): 4 chunks of float4
  int aRow[4], aKc[4];
  const float* aPtr[4];
#pragma unroll
  for (int h = 0; h < 4; ++h) {
    int c = tid + h * 256;
    aRow[h] = c >> 3; aKc[h] = (c & 7) * 4;
    aPtr[h] = x + (size_t)tokLds[aRow[h]] * DM + aKc[h];
  }

  float4 aR[4], bR[4];
#define G1_LOAD(k0)                                                  \
  {                                                                  \
    _Pragma("unroll")                                                \
    for (int h = 0; h < 4; ++h) aR[h] = *(const float4*)(aPtr[h] + (k0)); \
    const float* src = bBase + (size_t)(k0) * DH;                    \
    bR[0] = *(const float4*)src;                                     \
    bR[1] = *(const float4*)(src + 4);                               \
    bR[2] = *(const float4*)(src + DH);                              \
    bR[3] = *(const float4*)(src + DH + 4);                          \
  }

  G1_LOAD(0);
  for (int kt = 0; kt < DM / 32; ++kt) {
    __syncthreads();
    // store staged regs -> LDS (bf16)
#pragma unroll
    for (int h = 0; h < 4; ++h) {
      ushort4v wv = { f2bf(aR[h].x), f2bf(aR[h].y), f2bf(aR[h].z), f2bf(aR[h].w) };
      *(ushort4v*)&As[aRow[h] * PITCH + aKc[h]] = wv;
    }
    {
      float av[8] = {bR[0].x, bR[0].y, bR[0].z, bR[0].w, bR[1].x, bR[1].y, bR[1].z, bR[1].w};
      float bv[8] = {bR[2].x, bR[2].y, bR[2].z, bR[2].w, bR[3].x, bR[3].y, bR[3].z, bR[3].w};
#pragma unroll
      for (int j = 0; j < 8; ++j) {
        unsigned int wv = (unsigned int)f2bf(av[j]) | ((unsigned int)f2bf(bv[j]) << 16);
        *(unsigned int*)&BsM[(pn + j) * PITCH + pk] = wv;
      }
    }
    __syncthreads();
    if (kt + 1 < DM / 32) G1_LOAD((kt + 1) * 32);   // prefetch overlaps MFMA below
    bf16x8 a[4], f1[2], f2v[2];
#pragma unroll
    for (int mt = 0; mt < 4; ++mt)
      a[mt] = *(const bf16x8*)&As[(wm * 64 + mt * 16 + lr) * PITCH + quad * 8];
#pragma unroll
    for (int nt = 0; nt < 2; ++nt) {
      f1[nt]  = *(const bf16x8*)&Bs1[(wn * 32 + nt * 16 + lr) * PITCH + quad * 8];
      f2v[nt] = *(const bf16x8*)&Bs2[(wn * 32 + nt * 16 + lr) * PITCH + quad * 8];
    }
#pragma unroll
    for (int mt = 0; mt < 4; ++mt)
#pragma unroll
      for (int nt = 0; nt < 2; ++nt) {
        acc1[mt][nt] = __builtin_amdgcn_mfma_f32_16x16x32_bf16(a[mt], f1[nt],  acc1[mt][nt], 0, 0, 0);
        acc2[mt][nt] = __builtin_amdgcn_mfma_f32_16x16x32_bf16(a[mt], f2v[nt], acc2[mt][nt], 0, 0, 0);
      }
  }
  // epilogue: h = (t1+b1) * silu(t2+b2)  -> Hbuf bf16
  bf16_t* Hbuf = (bf16_t*)(ws + WS_HBUF);
#pragma unroll
  for (int mt = 0; mt < 4; ++mt) {
    int growb = wm * 64 + mt * 16 + quad * 4;   // C/D: row=(lane>>4)*4+reg, col=lane&15
#pragma unroll
    for (int nt = 0; nt < 2; ++nt) {
      int col = n0 + wn * 32 + nt * 16 + lr;
      float b1v = b1[e * DH + col];
      float b2v = b2[e * DH + col];
#pragma unroll
      for (int r = 0; r < 4; ++r) {
        int grow = growb + r;
        if (grow < m_cnt) {
          float v1 = acc1[mt][nt][r] + b1v;
          float v2 = acc2[mt][nt][r] + b2v;
          float hh = v1 * (v2 / (1.f + __expf(-v2)));
          Hbuf[(size_t)(m_start + grow) * DH + col] = __float2bfloat16(hh);
        }
      }
    }
  }
}

// ---------------- GEMM2: Y = wt * (H@wo + bo) per pair ----------------
// 256 thr = 4 waves (2x2), BM=128 slots, BN=128 model cols, BK=32, K=4096
__global__ __launch_bounds__(256, 2) void k_gemm2(const float* __restrict__ wo,
                                                  const float* __restrict__ bo,
                                                  char* __restrict__ ws) {
  __shared__ __align__(16) unsigned short As[128 * PITCH];
  __shared__ __align__(16) unsigned short Bs[128 * PITCH];
  int tid = threadIdx.x;
  int tileIdx = blockIdx.y;
  if (tileIdx >= *(const int*)(ws + WS_NTILES)) return;
  int e = ((const int*)(ws + WS_TILE_E))[tileIdx];
  int m_start = ((const int*)(ws + WS_TILE_M0))[tileIdx];
  int m_end = ((const int*)(ws + WS_OFFSETS))[e] + ((const int*)(ws + WS_COUNTS))[e];
  int m_cnt = min(128, m_end - m_start);
  int n0 = blockIdx.x * 128;
  const bf16_t* Hbuf = (const bf16_t*)(ws + WS_HBUF);

  f32x4 acc[4][4];
  f32x4 z = {0.f, 0.f, 0.f, 0.f};
#pragma unroll
  for (int i = 0; i < 4; ++i)
#pragma unroll
    for (int j = 0; j < 4; ++j) acc[i][j] = z;

  int lane = tid & 63, wave = tid >> 6;
  int wm = wave >> 1, wn = wave & 1;
  int lr = lane & 15, quad = lane >> 4;
  int pk = (tid & 15) * 2, pn = (tid >> 4) * 8;   // 256 patches of 2k x 8n
  const float* bBase = wo + ((size_t)e * DH + pk) * DM + n0 + pn;

  int aRow[2], aKc[2];
  const bf16_t* aPtr[2];
#pragma unroll
  for (int h = 0; h < 2; ++h) {
    int c = tid + h * 256;
    aRow[h] = c >> 2; aKc[h] = (c & 3) * 8;
    int hrow = m_start + min(aRow[h], m_cnt - 1);   // clamp: stay in written Hbuf
    aPtr[h] = Hbuf + (size_t)hrow * DH + aKc[h];
  }

  int4 aR[2]; float4 bR[4];
#define G2_LOAD(k0)                                                  \
  {                                                                  \
    _Pragma("unroll")                                                \
    for (int h = 0; h < 2; ++h) aR[h] = *(const int4*)(aPtr[h] + (k0)); \
    const float* src = bBase + (size_t)(k0) * DM;                    \
    bR[0] = *(const float4*)src;                                     \
    bR[1] = *(const float4*)(src + 4);                               \
    bR[2] = *(const float4*)(src + DM);                              \
    bR[3] = *(const float4*)(src + DM + 4);                          \
  }

  G2_LOAD(0);
  for (int kt = 0; kt < DH / 32; ++kt) {
    __syncthreads();
#pragma unroll
    for (int h = 0; h < 2; ++h)
      *(int4*)&As[aRow[h] * PITCH + aKc[h]] = aR[h];
    {
      float av[8] = {bR[0].x, bR[0].y, bR[0].z, bR[0].w, bR[1].x, bR[1].y, bR[1].z, bR[1].w};
      float bv[8] = {bR[2].x, bR[2].y, bR[2].z, bR[2].w, bR[3].x, bR[3].y, bR[3].z, bR[3].w};
#pragma unroll
      for (int j = 0; j < 8; ++j) {
        unsigned int wv = (unsigned int)f2bf(av[j]) | ((unsigned int)f2bf(bv[j]) << 16);
        *(unsigned int*)&Bs[(pn + j) * PITCH + pk] = wv;
      }
    }
    __syncthreads();
    if (kt + 1 < DH / 32) G2_LOAD((kt + 1) * 32);   // prefetch overlaps MFMA below
    bf16x8 a[4], b[4];
#pragma unroll
    for (int mt = 0; mt < 4; ++mt)
      a[mt] = *(const bf16x8*)&As[(wm * 64 + mt * 16 + lr) * PITCH + quad * 8];
#pragma unroll
    for (int nt = 0; nt < 4; ++nt)
      b[nt] = *(const bf16x8*)&Bs[(wn * 64 + nt * 16 + lr) * PITCH + quad * 8];
#pragma unroll
    for (int mt = 0; mt < 4; ++mt)
#pragma unroll
      for (int nt = 0; nt < 4; ++nt)
        acc[mt][nt] = __builtin_amdgcn_mfma_f32_16x16x32_bf16(a[mt], b[nt], acc[mt][nt], 0, 0, 0);
  }
  bf16_t* Ypair = (bf16_t*)(ws + WS_YPAIR);
  const float* wts = (const float*)(ws + WS_WT_OF);
#pragma unroll
  for (int mt = 0; mt < 4; ++mt) {
    int growb = wm * 64 + mt * 16 + quad * 4;
#pragma unroll
    for (int nt = 0; nt < 4; ++nt) {
      int col = n0 + wn * 64 + nt * 16 + lr;
      float bov = bo[e * DM + col];
#pragma unroll
      for (int r = 0; r < 4; ++r) {
        int grow = growb + r;
        if (grow < m_cnt) {
          int slot = m_start + grow;
          Ypair[(size_t)slot * DM + col] = __float2bfloat16((acc[mt][nt][r] + bov) * wts[slot]);
        }
      }
    }
  }
}

// ---------------- combine: out[t] = Y[slot(t,0)] + Y[slot(t,1)]  (f32 out) ----------------
__global__ __launch_bounds__(256) void k_combine(const char* __restrict__ ws,
                                                 float* __restrict__ out) {
  int idx = blockIdx.x * 256 + threadIdx.x;          // 8 cols each
  int t = idx >> 7, c = (idx & 127) * 8;
  const int* slot_of = (const int*)(ws + WS_SLOT_OF);
  int s0 = slot_of[2 * t], s1 = slot_of[2 * t + 1];
  const unsigned short* Y = (const unsigned short*)(ws + WS_YPAIR);
  int4 ya = *(const int4*)(Y + (size_t)s0 * DM + c);
  int4 yb = *(const int4*)(Y + (size_t)s1 * DM + c);
  const unsigned short* pa = (const unsigned short*)&ya;
  const unsigned short* pb = (const unsigned short*)&yb;
  float res[8];
#pragma unroll
  for (int j = 0; j < 8; ++j) {
    res[j] = __uint_as_float((unsigned int)pa[j] << 16) +
             __uint_as_float((unsigned int)pb[j] << 16);
  }
  float4 o0 = {res[0], res[1], res[2], res[3]};
  float4 o1 = {res[4], res[5], res[6], res[7]};
  *(float4*)(out + (size_t)t * DM + c) = o0;
  *(float4*)(out + (size_t)t * DM + c + 4) = o1;
}

extern "C" void kernel_launch(void* const* d_in, const int* in_sizes, int n_in,
                              void* d_out, int out_size, void* d_ws, size_t ws_size,
                              hipStream_t stream) {
  const float* x  = (const float*)d_in[0];
  const float* rw = (const float*)d_in[1];
  const float* rb = (const float*)d_in[2];
  const float* w1 = (const float*)d_in[3];
  const float* b1 = (const float*)d_in[4];
  const float* w2 = (const float*)d_in[5];
  const float* b2 = (const float*)d_in[6];
  const float* wo = (const float*)d_in[7];
  const float* bo = (const float*)d_in[8];
  float* out = (float*)d_out;
  char* ws = (char*)d_ws;
  if (ws_size < WS_NEEDED) return;

  hipMemsetAsync(d_ws, 0, 4096, stream);  // zero counts/psum/ntiles/cursor
  k_router<<<RT_BLOCKS, 256, 0, stream>>>(x, rw, rb, ws);
  k_scan<<<1, 64, 0, stream>>>(ws, out);
  k_fill<<<N_PAIRS / 256, 256, 0, stream>>>(ws);
  k_gemm1<<<dim3(DH / 64, MAX_TILES), 256, 0, stream>>>(x, w1, b1, w2, b2, ws);
  k_gemm2<<<dim3(DM / 128, MAX_TILES), 256, 0, stream>>>(wo, bo, ws);
  k_combine<<<(T_TOKENS * DM / 8) / 256, 256, 0, stream>>>(ws, out);
}